// Round 8
// baseline (76.350 us; speedup 1.0000x reference)
//
#include <hip/hip_runtime.h>
#include <hip/hip_cooperative_groups.h>

namespace cg = cooperative_groups;

#define B_   4
#define L_   1024
#define D_   16
#define H_   32
#define TAU_ 64
#define EMB_ 8
#define AEP_ 34   // ae_lds stride: even -> 8B-aligned float2 reads, 2-way banks (free)

typedef float f2 __attribute__((ext_vector_type(2)));

// ===========================================================================
// Fallback kernel 1: precompute (R6 verbatim)
// ===========================================================================
__global__ __launch_bounds__(256) void precompute_kernel(
    const float* __restrict__ x, const float* __restrict__ dtt,
    const float* __restrict__ W1, const float* __restrict__ b1,
    float* __restrict__ ai, float* __restrict__ aj, float* __restrict__ ae)
{
    const int id = blockIdx.x * 256 + threadIdx.x;
    const int NA = B_ * L_ * H_;
    if (id < NA) {
        const int h   = id & (H_ - 1);
        const int row = id >> 5;
        const float4* xr4 = (const float4*)(x + row * D_);
        const float4 v0 = xr4[0], v1 = xr4[1], v2 = xr4[2], v3 = xr4[3];
        const float xv[D_] = {v0.x, v0.y, v0.z, v0.w, v1.x, v1.y, v1.z, v1.w,
                              v2.x, v2.y, v2.z, v2.w, v3.x, v3.y, v3.z, v3.w};
        float s1 = 0.f, s2 = 0.f;
#pragma unroll
        for (int d = 0; d < D_; ++d) {
            s1 = fmaf(xv[d], W1[d * H_ + h], s1);
            s2 = fmaf(xv[d], W1[(D_ + d) * H_ + h], s2);
        }
        ai[id] = s1;
        aj[id] = s2;
    } else {
        const int k = id - NA;
        if (k < (TAU_ + 1) * H_) {
            const int h = k & (H_ - 1);
            const int t = k >> 5;
            float s = b1[h];
#pragma unroll
            for (int e = 0; e < EMB_; ++e)
                s = fmaf(dtt[t * EMB_ + e], W1[(2 * D_ + e) * H_ + h], s);
            ae[k] = s;
        }
    }
}

// ---------------------------------------------------------------------------
// Shared phase-2 body: one 64x64 tile. Assumes ae_lds staged (band tiles).
// ---------------------------------------------------------------------------
__device__ __forceinline__ void bias_tile(
    int b, int i0, int j0, int lane, int w,
    const float* __restrict__ ai, const float* __restrict__ aj,
    const float* __restrict__ ae, const float* __restrict__ W2, float b2,
    const float* __restrict__ ae_lds, float* __restrict__ out)
{
    const int j = j0 + lane;
    const bool c0  = (j0 >= i0 + 64);
    const bool c64 = (i0 >= j0 + 128);
    const bool constpath = c0 || c64;

    f2 r2[H_ / 2];
    {
        const float* ajr = aj + ((size_t)(b * L_ + j)) * H_;
#pragma unroll
        for (int h = 0; h < H_; h += 4) {
            const float4 v = *(const float4*)(ajr + h);
            r2[(h >> 1) + 0] = (f2){v.x, v.y};
            r2[(h >> 1) + 1] = (f2){v.z, v.w};
        }
    }

    if (constpath) {
        const float* aec = ae + (c0 ? 0 : TAU_) * H_;   // uniform -> s_load
#pragma unroll
        for (int h = 0; h < H_; h += 2) {
            const f2 e = {aec[h], aec[h + 1]};
            r2[h >> 1] += e;
        }
    }

    const float* aiBase = ai + ((size_t)(b * L_ + i0 + w * 16)) * H_;
    float* outb = out + ((size_t)b) * L_ * L_ + ((size_t)(i0 + w * 16)) * L_ + j;
    const f2 z2 = {0.f, 0.f};

    if (constpath) {
        const float pc = b2 - 0.2f * (c0 ? 0.f : (float)TAU_);
        for (int ii = 0; ii < 16; ii += 2) {
            const float* ar0 = aiBase + (ii + 0) * H_;   // uniform -> s_load
            const float* ar1 = aiBase + (ii + 1) * H_;
            f2 acc0 = z2, acc1 = z2;
#pragma unroll
            for (int h = 0; h < H_; h += 2) {
                const f2 wv = {W2[h], W2[h + 1]};
                const f2 a0 = {ar0[h], ar0[h + 1]};
                const f2 a1 = {ar1[h], ar1[h + 1]};
                f2 p0 = a0 + r2[h >> 1];
                f2 p1 = a1 + r2[h >> 1];
                p0 = __builtin_elementwise_max(p0, z2);
                p1 = __builtin_elementwise_max(p1, z2);
                acc0 = __builtin_elementwise_fma(p0, wv, acc0);
                acc1 = __builtin_elementwise_fma(p1, wv, acc1);
            }
            __builtin_nontemporal_store(acc0.x + acc0.y + pc, outb + (size_t)(ii + 0) * L_);
            __builtin_nontemporal_store(acc1.x + acc1.y + pc, outb + (size_t)(ii + 1) * L_);
        }
    } else {
        for (int ii = 0; ii < 16; ++ii) {
            const int i   = i0 + w * 16 + ii;
            const int d   = i - j;
            const int dt  = d < 0 ? 0 : (d > TAU_ ? TAU_ : d);
            const f2* eL  = (const f2*)&ae_lds[dt * AEP_];
            const float* ar = aiBase + ii * H_;
            f2 acc = z2;
#pragma unroll
            for (int h = 0; h < H_; h += 2) {
                const f2 wv = {W2[h], W2[h + 1]};
                const f2 a  = {ar[h], ar[h + 1]};
                f2 p = a + r2[h >> 1];
                p = p + eL[h >> 1];
                p = __builtin_elementwise_max(p, z2);
                acc = __builtin_elementwise_fma(p, wv, acc);
            }
            __builtin_nontemporal_store(acc.x + acc.y + b2 - 0.2f * (float)dt,
                                        outb + (size_t)ii * L_);
        }
    }
}

// ===========================================================================
// Fallback kernel 2: bias (R6 structure, shared tile body)
// ===========================================================================
__global__ __launch_bounds__(256, 4) void bias_kernel(
    const float* __restrict__ ai, const float* __restrict__ aj,
    const float* __restrict__ ae, const float* __restrict__ W2,
    const float* __restrict__ b2p, float* __restrict__ out)
{
    __shared__ float ae_lds[(TAU_ + 1) * AEP_];

    const int b    = blockIdx.z;
    const int i0   = blockIdx.y * 64;
    const int j0   = blockIdx.x * 64;
    const int tid  = threadIdx.x;
    const int lane = tid & 63;
    const int w    = __builtin_amdgcn_readfirstlane(tid >> 6);

    const bool band = !((j0 >= i0 + 64) || (i0 >= j0 + 128));
    if (band) {
        for (int k = tid; k < (TAU_ + 1) * H_; k += 256)
            ae_lds[(k >> 5) * AEP_ + (k & 31)] = ae[k];
        __syncthreads();
    }
    bias_tile(b, i0, j0, lane, w, ai, aj, ae, W2, *b2p, ae_lds, out);
}

// ===========================================================================
// Cooperative single-dispatch kernel: 512 blocks x 256 thr (2 blocks/CU).
// Phase 1: grid-strided precompute into workspace. grid.sync().
// Phase 2: ae table staged once; 2 tiles per block (t = bid, bid+512).
// ===========================================================================
__global__ __launch_bounds__(256, 4) void fused_coop_kernel(
    const float* __restrict__ x, const float* __restrict__ dtt,
    const float* __restrict__ W1, const float* __restrict__ b1,
    const float* __restrict__ W2, const float* __restrict__ b2p,
    float* __restrict__ ai, float* __restrict__ aj, float* __restrict__ ae,
    float* __restrict__ out)
{
    __shared__ float ae_lds[(TAU_ + 1) * AEP_];

    const int tid = threadIdx.x;
    const int bid = blockIdx.x;
    const int NA  = B_ * L_ * H_;
    const int NT  = NA + (TAU_ + 1) * H_;

    // ---- Phase 1: precompute (grid-strided) ----
    for (int id = bid * 256 + tid; id < NT; id += 512 * 256) {
        if (id < NA) {
            const int h   = id & (H_ - 1);
            const int row = id >> 5;
            const float4* xr4 = (const float4*)(x + row * D_);
            const float4 v0 = xr4[0], v1 = xr4[1], v2 = xr4[2], v3 = xr4[3];
            const float xv[D_] = {v0.x, v0.y, v0.z, v0.w, v1.x, v1.y, v1.z, v1.w,
                                  v2.x, v2.y, v2.z, v2.w, v3.x, v3.y, v3.z, v3.w};
            float s1 = 0.f, s2 = 0.f;
#pragma unroll
            for (int d = 0; d < D_; ++d) {
                s1 = fmaf(xv[d], W1[d * H_ + h], s1);
                s2 = fmaf(xv[d], W1[(D_ + d) * H_ + h], s2);
            }
            ai[id] = s1;
            aj[id] = s2;
        } else {
            const int k = id - NA;
            const int h = k & (H_ - 1);
            const int t = k >> 5;
            float s = b1[h];
#pragma unroll
            for (int e = 0; e < EMB_; ++e)
                s = fmaf(dtt[t * EMB_ + e], W1[(2 * D_ + e) * H_ + h], s);
            ae[k] = s;
        }
    }

    cg::this_grid().sync();

    // ---- Phase 2: stage ae table once, then 2 tiles per block ----
    for (int k = tid; k < (TAU_ + 1) * H_; k += 256)
        ae_lds[(k >> 5) * AEP_ + (k & 31)] = ae[k];
    __syncthreads();

    const int lane = tid & 63;
    const int w    = __builtin_amdgcn_readfirstlane(tid >> 6);
    const float b2 = *b2p;

#pragma unroll 1
    for (int t = bid; t < 1024; t += 512) {
        const int b  = t >> 8;
        const int i0 = ((t >> 4) & 15) * 64;
        const int j0 = (t & 15) * 64;
        bias_tile(b, i0, j0, lane, w, ai, aj, ae, W2, b2, ae_lds, out);
    }
}

extern "C" void kernel_launch(void* const* d_in, const int* in_sizes, int n_in,
                              void* d_out, int out_size, void* d_ws, size_t ws_size,
                              hipStream_t stream) {
    const float* x   = (const float*)d_in[0];
    const float* dtt = (const float*)d_in[1];
    const float* W1  = (const float*)d_in[2];
    const float* b1  = (const float*)d_in[3];
    const float* W2  = (const float*)d_in[4];
    const float* b2  = (const float*)d_in[5];
    float* out = (float*)d_out;

    float* ws = (float*)d_ws;
    float* ai = ws;                          // B*L*H floats
    float* aj = ws + B_ * L_ * H_;           // B*L*H floats
    float* ae = ws + 2 * B_ * L_ * H_;       // 65*H floats

    void* args[] = {(void*)&x, (void*)&dtt, (void*)&W1, (void*)&b1,
                    (void*)&W2, (void*)&b2, (void*)&ai, (void*)&aj,
                    (void*)&ae, (void*)&out};
    const hipError_t err = hipLaunchCooperativeKernel(
        (const void*)fused_coop_kernel, dim3(512), dim3(256), args, 0, stream);

    if (err != hipSuccess) {
        // Fallback: proven two-kernel path (R6).
        const int total  = B_ * L_ * H_ + (TAU_ + 1) * H_;
        const int blocks = (total + 255) / 256;
        hipLaunchKernelGGL(precompute_kernel, dim3(blocks), dim3(256), 0, stream,
                           x, dtt, W1, b1, ai, aj, ae);
        dim3 grid(L_ / 64, L_ / 64, B_);
        hipLaunchKernelGGL(bias_kernel, grid, dim3(256), 0, stream,
                           ai, aj, ae, W2, b2, out);
    }
}

// Round 9
// 28.069 us; speedup vs baseline: 2.7201x; 2.7201x over previous
//
#include <hip/hip_runtime.h>

#define B_   4
#define L_   1024
#define D_   16
#define H_   32
#define TAU_ 64
#define EMB_ 8
#define AEP_ 34   // ae_lds stride: even -> 8B-aligned float2 reads, 2-way banks (free)
#define TI_  32   // i-tile height: 2048 blocks = 8 blocks/CU -> 100% occupancy

typedef float f2 __attribute__((ext_vector_type(2)));

// ---------------------------------------------------------------------------
// Kernel 1: precompute (R6 verbatim)
//   ai[b,l,h] = x[b,l,:] @ W1[0:16, h]
//   aj[b,l,h] = x[b,l,:] @ W1[16:32, h]
//   ae[t,h]   = dt_table[t,:] @ W1[32:40, h] + b1[h]
// ---------------------------------------------------------------------------
__global__ __launch_bounds__(256) void precompute_kernel(
    const float* __restrict__ x, const float* __restrict__ dtt,
    const float* __restrict__ W1, const float* __restrict__ b1,
    float* __restrict__ ai, float* __restrict__ aj, float* __restrict__ ae)
{
    const int id = blockIdx.x * 256 + threadIdx.x;
    const int NA = B_ * L_ * H_;
    if (id < NA) {
        const int h   = id & (H_ - 1);
        const int row = id >> 5;                 // b*L + l
        const float4* xr4 = (const float4*)(x + row * D_);
        const float4 v0 = xr4[0], v1 = xr4[1], v2 = xr4[2], v3 = xr4[3];
        const float xv[D_] = {v0.x, v0.y, v0.z, v0.w, v1.x, v1.y, v1.z, v1.w,
                              v2.x, v2.y, v2.z, v2.w, v3.x, v3.y, v3.z, v3.w};
        float s1 = 0.f, s2 = 0.f;
#pragma unroll
        for (int d = 0; d < D_; ++d) {
            s1 = fmaf(xv[d], W1[d * H_ + h], s1);
            s2 = fmaf(xv[d], W1[(D_ + d) * H_ + h], s2);
        }
        ai[id] = s1;
        aj[id] = s2;
    } else {
        const int k = id - NA;
        if (k < (TAU_ + 1) * H_) {
            const int h = k & (H_ - 1);
            const int t = k >> 5;
            float s = b1[h];
#pragma unroll
            for (int e = 0; e < EMB_; ++e)
                s = fmaf(dtt[t * EMB_ + e], W1[(2 * D_ + e) * H_ + h], s);
            ae[k] = s;
        }
    }
}

// ---------------------------------------------------------------------------
// Kernel 2: bias kernel, high-occupancy edition.
// Tile 32 i x 64 j -> grid 2048 blocks = 8 blocks/CU; __launch_bounds__(256,8)
// (VGPR cap 64, measured need 56) -> 32 waves/CU = 100% occupancy for
// latency hiding (R8 coop profile showed VALUBusy 10.8% / Occupancy 21%:
// latency-bound, so more waves is the lever).
// lane = j (NT dword stores, coalesced); wave w owns rows i0+w*8..+7 via
// wave-uniform s_load pointers; packed-f32 (v_pk_*) inner loop.
// ---------------------------------------------------------------------------
__global__ __launch_bounds__(256, 8) void bias_kernel(
    const float* __restrict__ ai, const float* __restrict__ aj,
    const float* __restrict__ ae, const float* __restrict__ W2,
    const float* __restrict__ b2p, float* __restrict__ out)
{
    __shared__ float ae_lds[(TAU_ + 1) * AEP_];

    const int b    = blockIdx.z;
    const int i0   = blockIdx.y * TI_;
    const int j0   = blockIdx.x * 64;
    const int tid  = threadIdx.x;
    const int lane = tid & 63;
    const int w    = __builtin_amdgcn_readfirstlane(tid >> 6);
    const int j    = j0 + lane;

    // i range [i0, i0+31], j range [j0, j0+63]; i0 mult of 32, j0 mult of 64.
    const bool c0  = (j0 >= i0 + TI_);     // max(i)-min(j) <= 0 -> dt==0
    const bool c64 = (i0 >= j0 + 128);     // min(i)-max(j) >= 64 -> dt==64
    const bool constpath = c0 || c64;

    const float b2 = *b2p;

    // Per-lane column vector r2[h/2] = aj[j, h..h+1] (+ ae row on const path).
    f2 r2[H_ / 2];
    {
        const float* ajr = aj + ((size_t)(b * L_ + j)) * H_;
#pragma unroll
        for (int h = 0; h < H_; h += 4) {
            const float4 v = *(const float4*)(ajr + h);
            r2[(h >> 1) + 0] = (f2){v.x, v.y};
            r2[(h >> 1) + 1] = (f2){v.z, v.w};
        }
    }

    if (constpath) {
        const float* aec = ae + (c0 ? 0 : TAU_) * H_;   // uniform -> s_load
#pragma unroll
        for (int h = 0; h < H_; h += 2) {
            const f2 e = {aec[h], aec[h + 1]};
            r2[h >> 1] += e;
        }
    } else {
        for (int k = tid; k < (TAU_ + 1) * H_; k += 256)
            ae_lds[(k >> 5) * AEP_ + (k & 31)] = ae[k];
        __syncthreads();   // block-uniform branch
    }

    const float* aiBase = ai + ((size_t)(b * L_ + i0 + w * 8)) * H_;
    float* outb = out + ((size_t)b) * L_ * L_ + ((size_t)(i0 + w * 8)) * L_ + j;
    const f2 z2 = {0.f, 0.f};

    if (constpath) {
        const float pc = b2 - 0.2f * (c0 ? 0.f : (float)TAU_);
        for (int ii = 0; ii < 8; ii += 2) {
            const float* ar0 = aiBase + (ii + 0) * H_;   // uniform -> s_load
            const float* ar1 = aiBase + (ii + 1) * H_;
            f2 acc0 = z2, acc1 = z2;
#pragma unroll
            for (int h = 0; h < H_; h += 2) {
                const f2 wv = {W2[h], W2[h + 1]};        // sgpr pair
                const f2 a0 = {ar0[h], ar0[h + 1]};      // sgpr pair
                const f2 a1 = {ar1[h], ar1[h + 1]};
                f2 p0 = a0 + r2[h >> 1];                 // v_pk_add_f32
                f2 p1 = a1 + r2[h >> 1];
                p0 = __builtin_elementwise_max(p0, z2);  // v_pk_max_f32
                p1 = __builtin_elementwise_max(p1, z2);
                acc0 = __builtin_elementwise_fma(p0, wv, acc0);  // v_pk_fma_f32
                acc1 = __builtin_elementwise_fma(p1, wv, acc1);
            }
            __builtin_nontemporal_store(acc0.x + acc0.y + pc, outb + (size_t)(ii + 0) * L_);
            __builtin_nontemporal_store(acc1.x + acc1.y + pc, outb + (size_t)(ii + 1) * L_);
        }
    } else {
        for (int ii = 0; ii < 8; ++ii) {
            const int i   = i0 + w * 8 + ii;
            const int d   = i - j;
            const int dt  = d < 0 ? 0 : (d > TAU_ ? TAU_ : d);
            const f2* eL  = (const f2*)&ae_lds[dt * AEP_];   // 8B aligned
            const float* ar = aiBase + ii * H_;
            f2 acc = z2;
#pragma unroll
            for (int h = 0; h < H_; h += 2) {
                const f2 wv = {W2[h], W2[h + 1]};
                const f2 a  = {ar[h], ar[h + 1]};
                f2 p = a + r2[h >> 1];
                p = p + eL[h >> 1];
                p = __builtin_elementwise_max(p, z2);
                acc = __builtin_elementwise_fma(p, wv, acc);
            }
            __builtin_nontemporal_store(acc.x + acc.y + b2 - 0.2f * (float)dt,
                                        outb + (size_t)ii * L_);
        }
    }
}

extern "C" void kernel_launch(void* const* d_in, const int* in_sizes, int n_in,
                              void* d_out, int out_size, void* d_ws, size_t ws_size,
                              hipStream_t stream) {
    const float* x   = (const float*)d_in[0];
    const float* dtt = (const float*)d_in[1];
    const float* W1  = (const float*)d_in[2];
    const float* b1  = (const float*)d_in[3];
    const float* W2  = (const float*)d_in[4];
    const float* b2  = (const float*)d_in[5];
    float* out = (float*)d_out;

    float* ws = (float*)d_ws;
    float* ai = ws;                          // B*L*H floats
    float* aj = ws + B_ * L_ * H_;           // B*L*H floats
    float* ae = ws + 2 * B_ * L_ * H_;       // 65*H floats

    const int total  = B_ * L_ * H_ + (TAU_ + 1) * H_;
    const int blocks = (total + 255) / 256;
    hipLaunchKernelGGL(precompute_kernel, dim3(blocks), dim3(256), 0, stream,
                       x, dtt, W1, b1, ai, aj, ae);

    dim3 grid(L_ / 64, L_ / TI_, B_);
    hipLaunchKernelGGL(bias_kernel, grid, dim3(256), 0, stream,
                       ai, aj, ae, W2, b2, out);
}